// Round 2
// baseline (1990.165 us; speedup 1.0000x reference)
//
#include <hip/hip_runtime.h>
#include <math.h>

#define TOK 262144   // 64*64*64 voxels
#define NWIN 4096    // (64/4)^3 windows

__device__ __forceinline__ float wred_sum(float v){
  #pragma unroll
  for (int off = 32; off; off >>= 1) v += __shfl_xor(v, off);
  return v;
}
__device__ __forceinline__ float wred_max(float v){
  #pragma unroll
  for (int off = 32; off; off >>= 1) v = fmaxf(v, __shfl_xor(v, off));
  return v;
}

// ---------------- Kernel B: fused LN1 + window MHA + out-proj + doubling ----------------
// one block (256 thr = 4 waves) per window. LDS: 4 x 16KB fp32 = 64KB.
// kb holds K then att, XOR-swizzled to kill stride-64 bank conflicts.
__global__ __launch_bounds__(256) void k_attn(
    const float* __restrict__ x,
    const float* __restrict__ ln1g, const float* __restrict__ ln1b,
    const float* __restrict__ wq, const float* __restrict__ bq,
    const float* __restrict__ wk, const float* __restrict__ bk,
    const float* __restrict__ wv, const float* __restrict__ bv,
    const float* __restrict__ wo, const float* __restrict__ bo,
    float* __restrict__ obuf){
  __shared__ float hs[4096];
  __shared__ float qs[4096];   // q, later per-head o
  __shared__ float kb[4096];   // k (swizzled), later att (swizzled)
  __shared__ float vs[4096];
  int tid = threadIdx.x;
  int wg = tid >> 6, lane = tid & 63;
  int win = blockIdx.x;
  int d0 = (win >> 8) << 2, h0 = ((win >> 4) & 15) << 2, w0 = (win & 15) << 2;

  // ---- load window (coalesced 256B per wave per row) ----
  #pragma unroll
  for (int i = 0; i < 16; ++i){
    int l = i * 4 + wg;
    int gd = d0 + (l >> 4), gh = h0 + ((l >> 2) & 3), gw = w0 + (l & 3);
    hs[l * 64 + lane] = x[((gd * 64 + gh) * 64 + gw) * 64 + lane];
  }
  __syncthreads();

  // ---- LN1 on own rows ----
  float gv = ln1g[lane], bvv0 = ln1b[lane];
  #pragma unroll
  for (int j = 0; j < 16; ++j){
    int l = wg * 16 + j;
    float v = hs[l * 64 + lane];
    float m = wred_sum(v) * (1.0f/64.0f);
    float dv = v - m;
    float var = wred_sum(dv * dv) * (1.0f/64.0f);
    hs[l * 64 + lane] = dv * rsqrtf(var + 1e-5f) * gv + bvv0;
  }
  __syncthreads();

  float oacc[16];
  #pragma unroll
  for (int j = 0; j < 16; ++j) oacc[j] = 0.f;

  for (int hh = 0; hh < 4; ++hh){
    // ---- QKV: thread owns rows l = wg*16+j, col = lane ----
    float aq[16], ak[16], av[16];
    float bqv = bq[hh*64 + lane];
    float bkv = bk[hh*64 + lane];
    float bvv = bv[hh*64 + lane];
    #pragma unroll
    for (int j = 0; j < 16; ++j){ aq[j] = bqv; ak[j] = bkv; av[j] = bvv; }
    #pragma unroll 8
    for (int c = 0; c < 64; ++c){
      float wqv = wq[(c*4 + hh)*64 + lane];
      float wkv = wk[(c*4 + hh)*64 + lane];
      float wvv = wv[(c*4 + hh)*64 + lane];
      #pragma unroll
      for (int j = 0; j < 16; ++j){
        float hv = hs[(wg*16 + j)*64 + c];   // broadcast within wave
        aq[j] += hv * wqv; ak[j] += hv * wkv; av[j] += hv * wvv;
      }
    }
    #pragma unroll
    for (int j = 0; j < 16; ++j){
      int l = wg*16 + j;
      qs[l*64 + lane] = aq[j] * 0.125f;          // fold 1/sqrt(64)
      kb[l*64 + (lane ^ (l & 31))] = ak[j];      // swizzled store
      vs[l*64 + lane] = av[j];
    }
    __syncthreads();

    // ---- att[l][m] = q[l]·k[m], row m = lane ----
    float attr[16];
    #pragma unroll
    for (int j = 0; j < 16; ++j) attr[j] = 0.f;
    #pragma unroll 4
    for (int d = 0; d < 64; ++d){
      float kv = kb[lane*64 + (d ^ (lane & 31))];  // conflict-free via swizzle
      #pragma unroll
      for (int j = 0; j < 16; ++j)
        attr[j] += qs[(wg*16 + j)*64 + d] * kv;
    }
    __syncthreads();   // all k reads done; kb reusable
    #pragma unroll
    for (int j = 0; j < 16; ++j){
      int l = wg*16 + j;
      kb[l*64 + (lane ^ (l & 31))] = attr[j];
    }
    __syncthreads();

    // ---- softmax over m (lane = m) ----
    #pragma unroll
    for (int j = 0; j < 16; ++j){
      int l = wg*16 + j;
      int a = l*64 + (lane ^ (l & 31));
      float xv = kb[a];
      float mx = wred_max(xv);
      float e = expf(xv - mx);
      float s = wred_sum(e);
      kb[a] = e / s;
    }
    __syncthreads();

    // ---- o[l][d] = sum_m att[l][m] v[m][d], d = lane ----
    float orr[16];
    #pragma unroll
    for (int j = 0; j < 16; ++j) orr[j] = 0.f;
    #pragma unroll 4
    for (int m = 0; m < 64; ++m){
      float vv = vs[m*64 + lane];
      #pragma unroll
      for (int j = 0; j < 16; ++j){
        int l = wg*16 + j;
        orr[j] += kb[l*64 + (m ^ (l & 31))] * vv;
      }
    }
    __syncthreads();
    #pragma unroll
    for (int j = 0; j < 16; ++j) qs[(wg*16 + j)*64 + lane] = orr[j];
    __syncthreads();

    // ---- out-proj accumulate ----
    #pragma unroll 8
    for (int d = 0; d < 64; ++d){
      float wov = wo[(hh*64 + d)*64 + lane];
      #pragma unroll
      for (int j = 0; j < 16; ++j)
        oacc[j] += qs[(wg*16 + j)*64 + d] * wov;
    }
    __syncthreads();   // before next head rewrites qs/kb/vs
  }

  float bov = bo[lane];
  #pragma unroll
  for (int j = 0; j < 16; ++j){
    int l = wg*16 + j;
    int gd = d0 + (l >> 4);
    int gh = h0 + ((l >> 2) & 3);
    int gw = w0 + (l & 3);
    obuf[((gd*64 + gh)*64 + gw)*64 + lane] = 2.0f * (oacc[j] + bov);
  }
}

// ---------------- Kernel C: LN2 + FFN, 32 tokens/block (in-place safe) ----------------
__global__ __launch_bounds__(256) void k_ffn(
    const float* __restrict__ obuf,
    const float* __restrict__ g, const float* __restrict__ b,
    const float* __restrict__ w1, const float* __restrict__ b1,
    const float* __restrict__ w2, const float* __restrict__ b2,
    float* __restrict__ out){
  __shared__ float o2n[32*64];    // 8KB
  __shared__ float y1s[32*256];   // 32KB
  int tid = threadIdx.x, wg = tid >> 6, lane = tid & 63;
  int t0 = blockIdx.x * 32;
  float gv = g[lane], bvv = b[lane];
  #pragma unroll
  for (int j = 0; j < 8; ++j){
    int r = wg*8 + j;
    float v = obuf[(t0 + r)*64 + lane];
    float m = wred_sum(v) * (1.0f/64.0f);
    float dv = v - m;
    float var = wred_sum(dv * dv) * (1.0f/64.0f);
    o2n[r*64 + lane] = dv * rsqrtf(var + 1e-5f) * gv + bvv;
  }
  __syncthreads();

  float acc[8][4];
  #pragma unroll
  for (int j = 0; j < 8; ++j)
    #pragma unroll
    for (int jf = 0; jf < 4; ++jf) acc[j][jf] = b1[jf*64 + lane];

  #pragma unroll 4
  for (int c = 0; c < 64; ++c){
    float wa = w1[c*256 +       lane];
    float wb = w1[c*256 +  64 + lane];
    float wc = w1[c*256 + 128 + lane];
    float wd = w1[c*256 + 192 + lane];
    #pragma unroll
    for (int j = 0; j < 8; ++j){
      float hv = o2n[(wg*8 + j)*64 + c];   // broadcast
      acc[j][0] += hv * wa; acc[j][1] += hv * wb;
      acc[j][2] += hv * wc; acc[j][3] += hv * wd;
    }
  }
  #pragma unroll
  for (int j = 0; j < 8; ++j)
    #pragma unroll
    for (int jf = 0; jf < 4; ++jf){
      float a = acc[j][jf];
      y1s[(wg*8 + j)*256 + jf*64 + lane] = 0.5f * a * (1.0f + erff(a * 0.70710678118654752f));
    }
  __syncthreads();

  float o[8];
  #pragma unroll
  for (int j = 0; j < 8; ++j) o[j] = b2[lane];
  #pragma unroll 4
  for (int fc = 0; fc < 64; ++fc){
    float wa = w2[(fc*4 + 0)*64 + lane];
    float wb = w2[(fc*4 + 1)*64 + lane];
    float wc = w2[(fc*4 + 2)*64 + lane];
    float wd = w2[(fc*4 + 3)*64 + lane];
    #pragma unroll
    for (int j = 0; j < 8; ++j){
      const float4 y4 = *(const float4*)&y1s[(wg*8 + j)*256 + fc*4];
      o[j] += y4.x*wa + y4.y*wb + y4.z*wc + y4.w*wd;
    }
  }
  #pragma unroll
  for (int j = 0; j < 8; ++j)
    out[(t0 + wg*8 + j)*64 + lane] = o[j];
}

extern "C" void kernel_launch(void* const* d_in, const int* in_sizes, int n_in,
                              void* d_out, int out_size, void* d_ws, size_t ws_size,
                              hipStream_t stream){
  const float* x    = (const float*)d_in[0];
  const float* ln1g = (const float*)d_in[1];
  const float* ln1b = (const float*)d_in[2];
  const float* wq   = (const float*)d_in[3];
  const float* bq   = (const float*)d_in[4];
  const float* wk   = (const float*)d_in[5];
  const float* bk   = (const float*)d_in[6];
  const float* wv   = (const float*)d_in[7];
  const float* bv   = (const float*)d_in[8];
  const float* wo   = (const float*)d_in[9];
  const float* bo   = (const float*)d_in[10];
  const float* ln2g = (const float*)d_in[11];
  const float* ln2b = (const float*)d_in[12];
  const float* w1   = (const float*)d_in[13];
  const float* b1   = (const float*)d_in[14];
  const float* w2   = (const float*)d_in[15];
  const float* b2   = (const float*)d_in[16];

  float* obuf = (float*)d_out;   // attention output staged in d_out, rewritten in place by k_ffn
  float* out  = (float*)d_out;

  k_attn<<<NWIN, 256, 0, stream>>>(x, ln1g, ln1b, wq, bq, wk, bk, wv, bv, wo, bo, obuf);
  k_ffn<<<TOK/32, 256, 0, stream>>>(obuf, ln2g, ln2b, w1, b1, w2, b2, out);
}

// Round 3
// 547.420 us; speedup vs baseline: 3.6355x; 3.6355x over previous
//
#include <hip/hip_runtime.h>
#include <math.h>

#define TOK 262144   // 64*64*64 voxels
#define NWIN 4096    // (64/4)^3 windows

typedef unsigned short u16;
typedef __bf16 bf16;
typedef __attribute__((ext_vector_type(8))) __bf16 bf16x8;
typedef __attribute__((ext_vector_type(4))) float f32x4;

__device__ __forceinline__ u16 f2b(float f){
  return __builtin_bit_cast(u16, (bf16)f);
}
__device__ __forceinline__ float wred_sum(float v){
  #pragma unroll
  for (int off = 32; off; off >>= 1) v += __shfl_xor(v, off);
  return v;
}

// ---- LDS fragment helpers: [64][64] bf16 tiles, XOR-swizzled (ushort col ^ ((row&7)<<3)) ----
__device__ __forceinline__ bf16x8 ldfrag(const u16* m, int rowbase, int colbase, int lane){
  int row = rowbase + (lane & 15);
  int col = colbase + ((lane >> 4) << 3);
  return *(const bf16x8*)&m[row * 64 + (col ^ ((row & 7) << 3))];
}
__device__ __forceinline__ void stfrag(u16* m, int rowbase, int colbase, f32x4 v, float s, int lane){
  int col = colbase + (lane & 15);
  int r0  = rowbase + ((lane >> 4) << 2);
  #pragma unroll
  for (int r = 0; r < 4; ++r){
    int row = r0 + r;
    m[row * 64 + (col ^ ((row & 7) << 3))] = f2b(v[r] * s);
  }
}
// store transposed: element (row,col) -> m[col][row]
__device__ __forceinline__ void stfragT(u16* m, int rowbase, int colbase, f32x4 v, int lane){
  int col = colbase + (lane & 15);
  int r0  = rowbase + ((lane >> 4) << 2);
  #pragma unroll
  for (int r = 0; r < 4; ++r){
    int row = r0 + r;
    m[col * 64 + (row ^ ((col & 7) << 3))] = f2b(v[r]);
  }
}

// ---------------- prep: weights -> bf16 B-fragment order in d_ws ----------------
// wfq: [mat3][head4][kk2][ct4][lane64][8]  (49152 u16)
// wfo: [kk8][ct4][lane64][8]               (16384 u16)
__global__ __launch_bounds__(256) void k_prep(
    const float* __restrict__ wq, const float* __restrict__ wk,
    const float* __restrict__ wv, const float* __restrict__ wo,
    u16* __restrict__ wfq, u16* __restrict__ wfo){
  int idx = blockIdx.x * 256 + threadIdx.x;
  if (idx < 49152){
    int e = idx & 7, lane = (idx >> 3) & 63, ct = (idx >> 9) & 3;
    int kk = (idx >> 11) & 1, hh = (idx >> 12) & 3, m = idx >> 14;
    int c = kk * 32 + ((lane >> 4) << 3) + e;   // input channel (K dim)
    int d = (ct << 4) + (lane & 15);            // output col
    const float* W = (m == 0) ? wq : ((m == 1) ? wk : wv);
    wfq[idx] = f2b(W[(c * 4 + hh) * 64 + d]);
  } else {
    int j = idx - 49152;
    int e = j & 7, lane = (j >> 3) & 63, ct = (j >> 9) & 3, kk = (j >> 11) & 7;
    int k = kk * 32 + ((lane >> 4) << 3) + e;   // K dim (head*64+d)
    int c = (ct << 4) + (lane & 15);            // output channel
    wfo[j] = f2b(wo[k * 64 + c]);
  }
}

// ---------------- fused LN1 + window MHA + out-proj + doubling (MFMA) ----------------
// one block (4 waves) per window; wave owns 16 token rows.
__global__ __launch_bounds__(256) void k_attn(
    const float* __restrict__ x,
    const float* __restrict__ ln1g, const float* __restrict__ ln1b,
    const float* __restrict__ bq, const float* __restrict__ bk,
    const float* __restrict__ bv, const float* __restrict__ bo,
    const u16* __restrict__ wfq, const u16* __restrict__ wfo,
    float* __restrict__ obuf){
  __shared__ alignas(16) u16 hs[4096];   // LN1(x), [token][c]
  __shared__ alignas(16) u16 qs[4096];   // Q (scaled); later reused for per-head O
  __shared__ alignas(16) u16 ks[4096];   // K [m][d]
  __shared__ alignas(16) u16 vt[4096];   // V transposed [d][m]
  __shared__ alignas(16) u16 ps[4096];   // softmax(P) [token][m]
  int tid = threadIdx.x, wg = tid >> 6, lane = tid & 63;
  int win = blockIdx.x;
  int d0 = (win >> 8) << 2, h0 = ((win >> 4) & 15) << 2, w0 = (win & 15) << 2;
  int tb = wg * 16;

  // ---- load own rows + LN1 -> hs (bf16, swizzled). Own-rows only: no barrier. ----
  float gv = ln1g[lane], bb = ln1b[lane];
  #pragma unroll
  for (int j = 0; j < 16; ++j){
    int l = tb + j;
    int gd = d0 + (l >> 4), gh = h0 + ((l >> 2) & 3), gw = w0 + (l & 3);
    float v = x[((gd * 64 + gh) * 64 + gw) * 64 + lane];
    float mn = wred_sum(v) * 0.015625f;
    float dv = v - mn;
    float var = wred_sum(dv * dv) * 0.015625f;
    float n = dv * rsqrtf(var + 1e-5f) * gv + bb;
    hs[l * 64 + (lane ^ ((l & 7) << 3))] = f2b(n);
  }

  f32x4 oacc[4];
  #pragma unroll
  for (int ct = 0; ct < 4; ++ct){
    float b0 = bo[ct * 16 + (lane & 15)];
    oacc[ct] = (f32x4){b0, b0, b0, b0};
  }

  for (int hh = 0; hh < 4; ++hh){
    // ---- QKV projection (A = hs own rows, B = weight frags from global) ----
    f32x4 qa[4], ka[4], va[4];
    #pragma unroll
    for (int ct = 0; ct < 4; ++ct){
      float bqv = bq[hh * 64 + ct * 16 + (lane & 15)];
      float bkv = bk[hh * 64 + ct * 16 + (lane & 15)];
      float bvv = bv[hh * 64 + ct * 16 + (lane & 15)];
      qa[ct] = (f32x4){bqv, bqv, bqv, bqv};
      ka[ct] = (f32x4){bkv, bkv, bkv, bkv};
      va[ct] = (f32x4){bvv, bvv, bvv, bvv};
    }
    #pragma unroll
    for (int kk = 0; kk < 2; ++kk){
      bf16x8 a = ldfrag(hs, tb, kk * 32, lane);
      const u16* base = wfq + ((hh * 2 + kk) * 4) * 512 + lane * 8;
      #pragma unroll
      for (int ct = 0; ct < 4; ++ct){
        bf16x8 bw;
        bw = *(const bf16x8*)(base + ct * 512);                 // wq
        qa[ct] = __builtin_amdgcn_mfma_f32_16x16x32_bf16(a, bw, qa[ct], 0, 0, 0);
        bw = *(const bf16x8*)(base + 16384 + ct * 512);         // wk (mat stride 4*2*4*512)
        ka[ct] = __builtin_amdgcn_mfma_f32_16x16x32_bf16(a, bw, ka[ct], 0, 0, 0);
        bw = *(const bf16x8*)(base + 32768 + ct * 512);         // wv
        va[ct] = __builtin_amdgcn_mfma_f32_16x16x32_bf16(a, bw, va[ct], 0, 0, 0);
      }
    }
    #pragma unroll
    for (int ct = 0; ct < 4; ++ct){
      stfrag(qs, tb, ct * 16, qa[ct], 0.125f, lane);  // fold 1/sqrt(64)
      stfrag(ks, tb, ct * 16, ka[ct], 1.0f, lane);
      stfragT(vt, tb, ct * 16, va[ct], lane);
    }
    __syncthreads();   // ks/vt are read cross-wave

    // ---- att = Q K^T : A = qs own rows, B = ks rows (col j = m) ----
    f32x4 att[4];
    #pragma unroll
    for (int ct = 0; ct < 4; ++ct) att[ct] = (f32x4){0.f, 0.f, 0.f, 0.f};
    #pragma unroll
    for (int kk = 0; kk < 2; ++kk){
      bf16x8 a = ldfrag(qs, tb, kk * 32, lane);
      #pragma unroll
      for (int ct = 0; ct < 4; ++ct)
        att[ct] = __builtin_amdgcn_mfma_f32_16x16x32_bf16(
            a, ldfrag(ks, ct * 16, kk * 32, lane), att[ct], 0, 0, 0);
    }

    // ---- in-register softmax over m (64 values per token row, spread over
    //      4 fragments x 16 lanes of the row group; reduce via xor 1,2,4,8) ----
    #pragma unroll
    for (int r = 0; r < 4; ++r){
      float m0 = fmaxf(fmaxf(att[0][r], att[1][r]), fmaxf(att[2][r], att[3][r]));
      m0 = fmaxf(m0, __shfl_xor(m0, 1));
      m0 = fmaxf(m0, __shfl_xor(m0, 2));
      m0 = fmaxf(m0, __shfl_xor(m0, 4));
      m0 = fmaxf(m0, __shfl_xor(m0, 8));
      float e0 = expf(att[0][r] - m0), e1 = expf(att[1][r] - m0);
      float e2 = expf(att[2][r] - m0), e3 = expf(att[3][r] - m0);
      float s = e0 + e1 + e2 + e3;
      s += __shfl_xor(s, 1); s += __shfl_xor(s, 2);
      s += __shfl_xor(s, 4); s += __shfl_xor(s, 8);
      float inv = 1.0f / s;
      att[0][r] = e0 * inv; att[1][r] = e1 * inv;
      att[2][r] = e2 * inv; att[3][r] = e3 * inv;
    }
    #pragma unroll
    for (int ct = 0; ct < 4; ++ct) stfrag(ps, tb, ct * 16, att[ct], 1.0f, lane);

    // ---- O_h = P V : A = ps own rows, B = vt (col j = d, k = m) ----
    f32x4 oh[4];
    #pragma unroll
    for (int ct = 0; ct < 4; ++ct) oh[ct] = (f32x4){0.f, 0.f, 0.f, 0.f};
    #pragma unroll
    for (int kk = 0; kk < 2; ++kk){
      bf16x8 a = ldfrag(ps, tb, kk * 32, lane);
      #pragma unroll
      for (int ct = 0; ct < 4; ++ct)
        oh[ct] = __builtin_amdgcn_mfma_f32_16x16x32_bf16(
            a, ldfrag(vt, ct * 16, kk * 32, lane), oh[ct], 0, 0, 0);
    }
    #pragma unroll
    for (int ct = 0; ct < 4; ++ct) stfrag(qs, tb, ct * 16, oh[ct], 1.0f, lane); // reuse qs (wave-private)

    // ---- out-proj accumulate: oacc += O_h x Wo[h] ----
    #pragma unroll
    for (int kkl = 0; kkl < 2; ++kkl){
      bf16x8 a = ldfrag(qs, tb, kkl * 32, lane);
      const u16* base = wfo + ((hh * 2 + kkl) * 4) * 512 + lane * 8;
      #pragma unroll
      for (int ct = 0; ct < 4; ++ct)
        oacc[ct] = __builtin_amdgcn_mfma_f32_16x16x32_bf16(
            a, *(const bf16x8*)(base + ct * 512), oacc[ct], 0, 0, 0);
    }
    __syncthreads();   // before next head overwrites ks/vt
  }

  // ---- doubled output, merged voxel layout ----
  #pragma unroll
  for (int ct = 0; ct < 4; ++ct){
    int c = ct * 16 + (lane & 15);
    #pragma unroll
    for (int r = 0; r < 4; ++r){
      int l = tb + ((lane >> 4) << 2) + r;
      int gd = d0 + (l >> 4), gh = h0 + ((l >> 2) & 3), gw = w0 + (l & 3);
      obuf[((gd * 64 + gh) * 64 + gw) * 64 + c] = 2.0f * oacc[ct][r];
    }
  }
}

// ---------------- Kernel C: LN2 + FFN, 32 tokens/block (in-place safe) ----------------
__global__ __launch_bounds__(256) void k_ffn(
    const float* __restrict__ obuf,
    const float* __restrict__ g, const float* __restrict__ b,
    const float* __restrict__ w1, const float* __restrict__ b1,
    const float* __restrict__ w2, const float* __restrict__ b2,
    float* __restrict__ out){
  __shared__ float o2n[32*64];    // 8KB
  __shared__ float y1s[32*256];   // 32KB
  int tid = threadIdx.x, wg = tid >> 6, lane = tid & 63;
  int t0 = blockIdx.x * 32;
  float gv = g[lane], bvv = b[lane];
  #pragma unroll
  for (int j = 0; j < 8; ++j){
    int r = wg*8 + j;
    float v = obuf[(t0 + r)*64 + lane];
    float m = wred_sum(v) * (1.0f/64.0f);
    float dv = v - m;
    float var = wred_sum(dv * dv) * (1.0f/64.0f);
    o2n[r*64 + lane] = dv * rsqrtf(var + 1e-5f) * gv + bvv;
  }
  __syncthreads();

  float acc[8][4];
  #pragma unroll
  for (int j = 0; j < 8; ++j)
    #pragma unroll
    for (int jf = 0; jf < 4; ++jf) acc[j][jf] = b1[jf*64 + lane];

  #pragma unroll 4
  for (int c = 0; c < 64; ++c){
    float wa = w1[c*256 +       lane];
    float wb = w1[c*256 +  64 + lane];
    float wc = w1[c*256 + 128 + lane];
    float wd = w1[c*256 + 192 + lane];
    #pragma unroll
    for (int j = 0; j < 8; ++j){
      float hv = o2n[(wg*8 + j)*64 + c];   // broadcast
      acc[j][0] += hv * wa; acc[j][1] += hv * wb;
      acc[j][2] += hv * wc; acc[j][3] += hv * wd;
    }
  }
  #pragma unroll
  for (int j = 0; j < 8; ++j)
    #pragma unroll
    for (int jf = 0; jf < 4; ++jf){
      float a = acc[j][jf];
      y1s[(wg*8 + j)*256 + jf*64 + lane] = 0.5f * a * (1.0f + erff(a * 0.70710678118654752f));
    }
  __syncthreads();

  float o[8];
  #pragma unroll
  for (int j = 0; j < 8; ++j) o[j] = b2[lane];
  #pragma unroll 4
  for (int fc = 0; fc < 64; ++fc){
    float wa = w2[(fc*4 + 0)*64 + lane];
    float wb = w2[(fc*4 + 1)*64 + lane];
    float wc = w2[(fc*4 + 2)*64 + lane];
    float wd = w2[(fc*4 + 3)*64 + lane];
    #pragma unroll
    for (int j = 0; j < 8; ++j){
      const float4 y4 = *(const float4*)&y1s[(wg*8 + j)*256 + fc*4];
      o[j] += y4.x*wa + y4.y*wb + y4.z*wc + y4.w*wd;
    }
  }
  #pragma unroll
  for (int j = 0; j < 8; ++j)
    out[(t0 + wg*8 + j)*64 + lane] = o[j];
}

extern "C" void kernel_launch(void* const* d_in, const int* in_sizes, int n_in,
                              void* d_out, int out_size, void* d_ws, size_t ws_size,
                              hipStream_t stream){
  const float* x    = (const float*)d_in[0];
  const float* ln1g = (const float*)d_in[1];
  const float* ln1b = (const float*)d_in[2];
  const float* wq   = (const float*)d_in[3];
  const float* bq   = (const float*)d_in[4];
  const float* wk   = (const float*)d_in[5];
  const float* bk   = (const float*)d_in[6];
  const float* wv   = (const float*)d_in[7];
  const float* bv   = (const float*)d_in[8];
  const float* wo   = (const float*)d_in[9];
  const float* bo   = (const float*)d_in[10];
  const float* ln2g = (const float*)d_in[11];
  const float* ln2b = (const float*)d_in[12];
  const float* w1   = (const float*)d_in[13];
  const float* b1   = (const float*)d_in[14];
  const float* w2   = (const float*)d_in[15];
  const float* b2   = (const float*)d_in[16];

  u16* wfq = (u16*)d_ws;           // 96KB
  u16* wfo = wfq + 49152;          // 32KB
  float* obuf = (float*)d_out;     // staged in d_out, rewritten in place by k_ffn
  float* out  = (float*)d_out;

  k_prep<<<256, 256, 0, stream>>>(wq, wk, wv, wo, wfq, wfo);
  k_attn<<<NWIN, 256, 0, stream>>>(x, ln1g, ln1b, bq, bk, bv, bo, wfq, wfo, obuf);
  k_ffn<<<TOK/32, 256, 0, stream>>>(obuf, ln2g, ln2b, w1, b1, w2, b2, out);
}

// Round 4
// 403.468 us; speedup vs baseline: 4.9326x; 1.3568x over previous
//
#include <hip/hip_runtime.h>
#include <math.h>

#define NWIN 4096    // (64/4)^3 windows

typedef unsigned short u16;
typedef __bf16 bf16;
typedef __attribute__((ext_vector_type(8))) __bf16 bf16x8;
typedef __attribute__((ext_vector_type(4))) float f32x4;

__device__ __forceinline__ u16 f2b(float f){
  return __builtin_bit_cast(u16, (bf16)f);
}
__device__ __forceinline__ float wred_sum(float v){
  #pragma unroll
  for (int off = 32; off; off >>= 1) v += __shfl_xor(v, off);
  return v;
}
__device__ __forceinline__ float grp16_sum(float v){
  v += __shfl_xor(v, 1); v += __shfl_xor(v, 2);
  v += __shfl_xor(v, 4); v += __shfl_xor(v, 8);
  return v;
}

// ---- LDS fragment helpers: bf16 tiles, XOR-swizzled (col ^ ((row&7)<<3)) ----
template<int STRIDE>
__device__ __forceinline__ bf16x8 ldfrag(const u16* m, int rowbase, int colbase, int lane){
  int row = rowbase + (lane & 15);
  int col = colbase + ((lane >> 4) << 3);
  return *(const bf16x8*)&m[row * STRIDE + (col ^ ((row & 7) << 3))];
}
template<int STRIDE>
__device__ __forceinline__ void stfrag(u16* m, int rowbase, int colbase, f32x4 v, float s, int lane){
  int col = colbase + (lane & 15);
  int r0  = rowbase + ((lane >> 4) << 2);
  #pragma unroll
  for (int r = 0; r < 4; ++r){
    int row = r0 + r;
    m[row * STRIDE + (col ^ ((row & 7) << 3))] = f2b(v[r] * s);
  }
}
// store transposed: element (row,col) -> m[col][row]
__device__ __forceinline__ void stfragT(u16* m, int rowbase, int colbase, f32x4 v, int lane){
  int col = colbase + (lane & 15);
  int r0  = rowbase + ((lane >> 4) << 2);
  #pragma unroll
  for (int r = 0; r < 4; ++r){
    int row = r0 + r;
    m[col * 64 + (row ^ ((col & 7) << 3))] = f2b(v[r]);
  }
}

// ---------------- prep: weights -> bf16 B-fragment order in d_ws ----------------
// wfq: [mat3][head4][kk2][ct4][lane64][8]   49152 u16
// wfo: [kk8][ct4][lane64][8]                16384 u16
// wf1: [kk2][nt16][lane64][8]               16384 u16
// wf2: [kk8][nt4][lane64][8]                16384 u16
__global__ __launch_bounds__(256) void k_prep(
    const float* __restrict__ wq, const float* __restrict__ wk,
    const float* __restrict__ wv, const float* __restrict__ wo,
    const float* __restrict__ w1, const float* __restrict__ w2,
    u16* __restrict__ wfq){
  int idx = blockIdx.x * 256 + threadIdx.x;
  int e = idx & 7, lane = (idx >> 3) & 63;
  if (idx < 49152){
    int ct = (idx >> 9) & 3, kk = (idx >> 11) & 1, hh = (idx >> 12) & 3, m = idx >> 14;
    int c = kk * 32 + ((lane >> 4) << 3) + e;
    int d = (ct << 4) + (lane & 15);
    const float* W = (m == 0) ? wq : ((m == 1) ? wk : wv);
    wfq[idx] = f2b(W[(c * 4 + hh) * 64 + d]);
  } else if (idx < 65536){
    int j = idx - 49152;
    int ct = (j >> 9) & 3, kk = (j >> 11) & 7;
    int k = kk * 32 + ((lane >> 4) << 3) + e;
    int c = (ct << 4) + (lane & 15);
    wfq[idx] = f2b(wo[k * 64 + c]);
  } else if (idx < 81920){
    int j = idx - 65536;
    int nt = (j >> 9) & 15, kk = (j >> 13) & 1;
    int c = kk * 32 + ((lane >> 4) << 3) + e;
    int f = nt * 16 + (lane & 15);
    wfq[idx] = f2b(w1[c * 256 + f]);
  } else {
    int j = idx - 81920;
    int nt = (j >> 9) & 3, kk = (j >> 11) & 7;
    int f = kk * 32 + ((lane >> 4) << 3) + e;
    int c = nt * 16 + (lane & 15);
    wfq[idx] = f2b(w2[f * 64 + c]);
  }
}

// ------- fused LN1 + window MHA + out-proj + x2 + LN2 + FFN (all MFMA) -------
// one block (4 waves) per window; wave owns 16 token rows. 40KB LDS.
__global__ __launch_bounds__(256) void k_mega(
    const float* __restrict__ x,
    const float* __restrict__ ln1g, const float* __restrict__ ln1b,
    const float* __restrict__ bq, const float* __restrict__ bk,
    const float* __restrict__ bv, const float* __restrict__ bo,
    const float* __restrict__ ln2g, const float* __restrict__ ln2b,
    const float* __restrict__ b1, const float* __restrict__ b2,
    const u16* __restrict__ wf,
    float* __restrict__ out){
  __shared__ alignas(16) u16 sh[20480];   // 40KB
  u16* hs = sh;           // [64][64] LN1(x); later LN2 result
  u16* qs = sh + 4096;    // Q; later per-head O; later y1 region (wg0)
  u16* ks = sh + 8192;    // K; later y1 (wg1)
  u16* vt = sh + 12288;   // V^T; later y1 (wg2)
  u16* ps = sh + 16384;   // P; later y1 (wg3)
  const u16* wfq = wf;
  const u16* wfo = wf + 49152;
  const u16* wf1 = wf + 65536;
  const u16* wf2 = wf + 81920;

  int tid = threadIdx.x, wg = tid >> 6, lane = tid & 63;
  int win = blockIdx.x;
  int d0 = (win >> 8) << 2, h0 = ((win >> 4) & 15) << 2, w0 = (win & 15) << 2;
  int tb = wg * 16;
  int c0 = lane & 15, g4 = (lane >> 4) << 2;

  // ---- load own rows + LN1 -> hs (bf16, swizzled). Own rows: no barrier. ----
  {
    float gv = ln1g[lane], bb = ln1b[lane];
    #pragma unroll
    for (int j = 0; j < 16; ++j){
      int l = tb + j;
      int gd = d0 + (l >> 4), gh = h0 + ((l >> 2) & 3), gw = w0 + (l & 3);
      float v = x[((gd * 64 + gh) * 64 + gw) * 64 + lane];
      float mn = wred_sum(v) * 0.015625f;
      float dv = v - mn;
      float var = wred_sum(dv * dv) * 0.015625f;
      float n = dv * rsqrtf(var + 1e-5f) * gv + bb;
      hs[l * 64 + (lane ^ ((l & 7) << 3))] = f2b(n);
    }
  }

  f32x4 oacc[4];
  #pragma unroll
  for (int ct = 0; ct < 4; ++ct){
    float b0 = bo[ct * 16 + c0];
    oacc[ct] = (f32x4){b0, b0, b0, b0};
  }

  for (int hh = 0; hh < 4; ++hh){
    // ---- QKV projection ----
    f32x4 qa[4], ka[4], va[4];
    #pragma unroll
    for (int ct = 0; ct < 4; ++ct){
      float bqv = bq[hh * 64 + ct * 16 + c0];
      float bkv = bk[hh * 64 + ct * 16 + c0];
      float bvv = bv[hh * 64 + ct * 16 + c0];
      qa[ct] = (f32x4){bqv, bqv, bqv, bqv};
      ka[ct] = (f32x4){bkv, bkv, bkv, bkv};
      va[ct] = (f32x4){bvv, bvv, bvv, bvv};
    }
    #pragma unroll
    for (int kk = 0; kk < 2; ++kk){
      bf16x8 a = ldfrag<64>(hs, tb, kk * 32, lane);
      const u16* base = wfq + ((hh * 2 + kk) * 4) * 512 + lane * 8;
      #pragma unroll
      for (int ct = 0; ct < 4; ++ct){
        bf16x8 bw;
        bw = *(const bf16x8*)(base + ct * 512);
        qa[ct] = __builtin_amdgcn_mfma_f32_16x16x32_bf16(a, bw, qa[ct], 0, 0, 0);
        bw = *(const bf16x8*)(base + 16384 + ct * 512);
        ka[ct] = __builtin_amdgcn_mfma_f32_16x16x32_bf16(a, bw, ka[ct], 0, 0, 0);
        bw = *(const bf16x8*)(base + 32768 + ct * 512);
        va[ct] = __builtin_amdgcn_mfma_f32_16x16x32_bf16(a, bw, va[ct], 0, 0, 0);
      }
    }
    #pragma unroll
    for (int ct = 0; ct < 4; ++ct){
      stfrag<64>(qs, tb, ct * 16, qa[ct], 0.125f, lane);
      stfrag<64>(ks, tb, ct * 16, ka[ct], 1.0f, lane);
      stfragT(vt, tb, ct * 16, va[ct], lane);
    }
    __syncthreads();   // ks/vt read cross-wave

    // ---- att = Q K^T ----
    f32x4 att[4];
    #pragma unroll
    for (int ct = 0; ct < 4; ++ct) att[ct] = (f32x4){0.f, 0.f, 0.f, 0.f};
    #pragma unroll
    for (int kk = 0; kk < 2; ++kk){
      bf16x8 a = ldfrag<64>(qs, tb, kk * 32, lane);
      #pragma unroll
      for (int ct = 0; ct < 4; ++ct)
        att[ct] = __builtin_amdgcn_mfma_f32_16x16x32_bf16(
            a, ldfrag<64>(ks, ct * 16, kk * 32, lane), att[ct], 0, 0, 0);
    }

    // ---- in-register softmax over m ----
    #pragma unroll
    for (int r = 0; r < 4; ++r){
      float m0 = fmaxf(fmaxf(att[0][r], att[1][r]), fmaxf(att[2][r], att[3][r]));
      m0 = fmaxf(m0, __shfl_xor(m0, 1));
      m0 = fmaxf(m0, __shfl_xor(m0, 2));
      m0 = fmaxf(m0, __shfl_xor(m0, 4));
      m0 = fmaxf(m0, __shfl_xor(m0, 8));
      float e0 = expf(att[0][r] - m0), e1 = expf(att[1][r] - m0);
      float e2 = expf(att[2][r] - m0), e3 = expf(att[3][r] - m0);
      float s = e0 + e1 + e2 + e3;
      s = grp16_sum(s);
      float inv = 1.0f / s;
      att[0][r] = e0 * inv; att[1][r] = e1 * inv;
      att[2][r] = e2 * inv; att[3][r] = e3 * inv;
    }
    #pragma unroll
    for (int ct = 0; ct < 4; ++ct) stfrag<64>(ps, tb, ct * 16, att[ct], 1.0f, lane);

    // ---- O_h = P V ----
    f32x4 oh[4];
    #pragma unroll
    for (int ct = 0; ct < 4; ++ct) oh[ct] = (f32x4){0.f, 0.f, 0.f, 0.f};
    #pragma unroll
    for (int kk = 0; kk < 2; ++kk){
      bf16x8 a = ldfrag<64>(ps, tb, kk * 32, lane);
      #pragma unroll
      for (int ct = 0; ct < 4; ++ct)
        oh[ct] = __builtin_amdgcn_mfma_f32_16x16x32_bf16(
            a, ldfrag<64>(vt, ct * 16, kk * 32, lane), oh[ct], 0, 0, 0);
    }
    #pragma unroll
    for (int ct = 0; ct < 4; ++ct) stfrag<64>(qs, tb, ct * 16, oh[ct], 1.0f, lane);

    // ---- out-proj accumulate ----
    #pragma unroll
    for (int kkl = 0; kkl < 2; ++kkl){
      bf16x8 a = ldfrag<64>(qs, tb, kkl * 32, lane);
      const u16* base = wfo + ((hh * 2 + kkl) * 4) * 512 + lane * 8;
      #pragma unroll
      for (int ct = 0; ct < 4; ++ct)
        oacc[ct] = __builtin_amdgcn_mfma_f32_16x16x32_bf16(
            a, *(const bf16x8*)(base + ct * 512), oacc[ct], 0, 0, 0);
    }
    __syncthreads();   // before next head overwrites ks/vt (and before FFN LDS reuse)
  }

  // ======== fused x2 + LN2 + FFN (wave-private from here: no barriers) ========
  // LN2 in-register on D-fragments: row l = tb + g4 + r lives in a 16-lane group.
  {
    float g2[4], b2l[4];
    #pragma unroll
    for (int ct = 0; ct < 4; ++ct){
      g2[ct] = ln2g[ct * 16 + c0];
      b2l[ct] = ln2b[ct * 16 + c0];
    }
    #pragma unroll
    for (int r = 0; r < 4; ++r){
      float v0 = 2.0f * oacc[0][r], v1 = 2.0f * oacc[1][r];
      float v2 = 2.0f * oacc[2][r], v3 = 2.0f * oacc[3][r];
      float s = grp16_sum(v0 + v1 + v2 + v3);
      float mn = s * 0.015625f;
      float d0f = v0 - mn, d1 = v1 - mn, d2 = v2 - mn, d3 = v3 - mn;
      float q = grp16_sum(d0f*d0f + d1*d1 + d2*d2 + d3*d3);
      float rs = rsqrtf(q * 0.015625f + 1e-5f);
      int row = tb + g4 + r;
      hs[row * 64 + ((0 * 16 + c0) ^ ((row & 7) << 3))] = f2b(d0f * rs * g2[0] + b2l[0]);
      hs[row * 64 + ((1 * 16 + c0) ^ ((row & 7) << 3))] = f2b(d1 * rs * g2[1] + b2l[1]);
      hs[row * 64 + ((2 * 16 + c0) ^ ((row & 7) << 3))] = f2b(d2 * rs * g2[2] + b2l[2]);
      hs[row * 64 + ((3 * 16 + c0) ^ ((row & 7) << 3))] = f2b(d3 * rs * g2[3] + b2l[3]);
    }
  }

  // ---- GEMM1: [16,64] x [64,256] -> y1 (GELU, bf16) in this wave's LDS region ----
  u16* y1w = sh + 4096 + wg * 4096;   // [16][256] bf16, swizzled
  {
    f32x4 acc1[16];
    #pragma unroll
    for (int nt = 0; nt < 16; ++nt){
      float bb = b1[nt * 16 + c0];
      acc1[nt] = (f32x4){bb, bb, bb, bb};
    }
    #pragma unroll
    for (int kk = 0; kk < 2; ++kk){
      bf16x8 a = ldfrag<64>(hs, tb, kk * 32, lane);
      const u16* base = wf1 + kk * 16 * 512 + lane * 8;
      #pragma unroll
      for (int nt = 0; nt < 16; ++nt)
        acc1[nt] = __builtin_amdgcn_mfma_f32_16x16x32_bf16(
            a, *(const bf16x8*)(base + nt * 512), acc1[nt], 0, 0, 0);
    }
    #pragma unroll
    for (int nt = 0; nt < 16; ++nt){
      f32x4 v = acc1[nt];
      f32x4 y;
      #pragma unroll
      for (int r = 0; r < 4; ++r)
        y[r] = 0.5f * v[r] * (1.0f + erff(v[r] * 0.70710678118654752f));
      stfrag<256>(y1w, 0, nt * 16, y, 1.0f, lane);
    }
  }

  // ---- GEMM2: [16,256] x [256,64] -> out (fp32, merged voxel layout) ----
  {
    f32x4 acc2[4];
    #pragma unroll
    for (int nt = 0; nt < 4; ++nt){
      float bb = b2[nt * 16 + c0];
      acc2[nt] = (f32x4){bb, bb, bb, bb};
    }
    #pragma unroll
    for (int kk = 0; kk < 8; ++kk){
      bf16x8 a = ldfrag<256>(y1w, 0, kk * 32, lane);
      const u16* base = wf2 + kk * 4 * 512 + lane * 8;
      #pragma unroll
      for (int nt = 0; nt < 4; ++nt)
        acc2[nt] = __builtin_amdgcn_mfma_f32_16x16x32_bf16(
            a, *(const bf16x8*)(base + nt * 512), acc2[nt], 0, 0, 0);
    }
    #pragma unroll
    for (int r = 0; r < 4; ++r){
      int l = tb + g4 + r;
      int gd = d0 + (l >> 4), gh = h0 + ((l >> 2) & 3), gw = w0 + (l & 3);
      float* orow = out + ((gd * 64 + gh) * 64 + gw) * 64;
      #pragma unroll
      for (int nt = 0; nt < 4; ++nt)
        orow[nt * 16 + c0] = acc2[nt][r];
    }
  }
}

extern "C" void kernel_launch(void* const* d_in, const int* in_sizes, int n_in,
                              void* d_out, int out_size, void* d_ws, size_t ws_size,
                              hipStream_t stream){
  const float* x    = (const float*)d_in[0];
  const float* ln1g = (const float*)d_in[1];
  const float* ln1b = (const float*)d_in[2];
  const float* wq   = (const float*)d_in[3];
  const float* bq   = (const float*)d_in[4];
  const float* wk   = (const float*)d_in[5];
  const float* bk   = (const float*)d_in[6];
  const float* wv   = (const float*)d_in[7];
  const float* bv   = (const float*)d_in[8];
  const float* wo   = (const float*)d_in[9];
  const float* bo   = (const float*)d_in[10];
  const float* ln2g = (const float*)d_in[11];
  const float* ln2b = (const float*)d_in[12];
  const float* w1   = (const float*)d_in[13];
  const float* b1   = (const float*)d_in[14];
  const float* w2   = (const float*)d_in[15];
  const float* b2   = (const float*)d_in[16];

  u16* wf = (u16*)d_ws;     // 192KB of bf16 weight fragments
  float* out = (float*)d_out;

  k_prep<<<384, 256, 0, stream>>>(wq, wk, wv, wo, w1, w2, wf);
  k_mega<<<NWIN, 256, 0, stream>>>(x, ln1g, ln1b, bq, bk, bv, bo,
                                   ln2g, ln2b, b1, b2, wf, out);
}

// Round 5
// 228.146 us; speedup vs baseline: 8.7232x; 1.7685x over previous
//
#include <hip/hip_runtime.h>
#include <math.h>

#define NWIN 4096    // (64/4)^3 windows

typedef unsigned short u16;
typedef __bf16 bf16;
typedef __attribute__((ext_vector_type(8))) __bf16 bf16x8;
typedef __attribute__((ext_vector_type(4))) float f32x4;

__device__ __forceinline__ u16 f2b(float f){
  return __builtin_bit_cast(u16, (bf16)f);
}
__device__ __forceinline__ float wred_sum(float v){
  #pragma unroll
  for (int off = 32; off; off >>= 1) v += __shfl_xor(v, off);
  return v;
}
__device__ __forceinline__ float grp16_sum(float v){
  v += __shfl_xor(v, 1); v += __shfl_xor(v, 2);
  v += __shfl_xor(v, 4); v += __shfl_xor(v, 8);
  return v;
}
// GELU with A&S 7.1.26 erf (max err 1.5e-7), ~12 VALU ops vs libm erff
__device__ __forceinline__ float gelu(float v){
  float t = v * 0.70710678118654752f;
  float a = fabsf(t);
  float k = __builtin_amdgcn_rcpf(1.0f + 0.3275911f * a);
  float p = k*(0.254829592f + k*(-0.284496736f + k*(1.421413741f + k*(-1.453152027f + k*1.061405429f))));
  float er = 1.0f - p * __expf(-a * a);
  er = (t < 0.f) ? -er : er;
  return 0.5f * v * (1.0f + er);
}

// ---- LDS fragment helpers: bf16 tiles, XOR-swizzled (col ^ ((row&7)<<3)) ----
template<int STRIDE>
__device__ __forceinline__ bf16x8 ldfrag(const u16* m, int rowbase, int colbase, int lane){
  int row = rowbase + (lane & 15);
  int col = colbase + ((lane >> 4) << 3);
  return *(const bf16x8*)&m[row * STRIDE + (col ^ ((row & 7) << 3))];
}
template<int STRIDE>
__device__ __forceinline__ void stfrag(u16* m, int rowbase, int colbase, f32x4 v, float s, int lane){
  int col = colbase + (lane & 15);
  int r0  = rowbase + ((lane >> 4) << 2);
  #pragma unroll
  for (int r = 0; r < 4; ++r){
    int row = r0 + r;
    m[row * STRIDE + (col ^ ((row & 7) << 3))] = f2b(v[r] * s);
  }
}
// store transposed: element (row,col) -> m[col][row]
__device__ __forceinline__ void stfragT(u16* m, int rowbase, int colbase, f32x4 v, int lane){
  int col = colbase + (lane & 15);
  int r0  = rowbase + ((lane >> 4) << 2);
  #pragma unroll
  for (int r = 0; r < 4; ++r){
    int row = r0 + r;
    m[col * 64 + (row ^ ((col & 7) << 3))] = f2b(v[r]);
  }
}

// ---------------- prep: weights -> bf16 B-fragment order in d_ws ----------------
// wfq: [mat3][head4][kk2][ct4][lane64][8]   49152 u16
// wfo: [kk8][ct4][lane64][8]                16384 u16
// wf1: [kk2][nt16][lane64][8]               16384 u16
// wf2: [kk8][nt4][lane64][8]                16384 u16
__global__ __launch_bounds__(256) void k_prep(
    const float* __restrict__ wq, const float* __restrict__ wk,
    const float* __restrict__ wv, const float* __restrict__ wo,
    const float* __restrict__ w1, const float* __restrict__ w2,
    u16* __restrict__ wfq){
  int idx = blockIdx.x * 256 + threadIdx.x;
  int e = idx & 7, lane = (idx >> 3) & 63;
  if (idx < 49152){
    int ct = (idx >> 9) & 3, kk = (idx >> 11) & 1, hh = (idx >> 12) & 3, m = idx >> 14;
    int c = kk * 32 + ((lane >> 4) << 3) + e;
    int d = (ct << 4) + (lane & 15);
    const float* W = (m == 0) ? wq : ((m == 1) ? wk : wv);
    wfq[idx] = f2b(W[(c * 4 + hh) * 64 + d]);
  } else if (idx < 65536){
    int j = idx - 49152;
    int ct = (j >> 9) & 3, kk = (j >> 11) & 7;
    int k = kk * 32 + ((lane >> 4) << 3) + e;
    int c = (ct << 4) + (lane & 15);
    wfq[idx] = f2b(wo[k * 64 + c]);
  } else if (idx < 81920){
    int j = idx - 65536;
    int nt = (j >> 9) & 15, kk = (j >> 13) & 1;
    int c = kk * 32 + ((lane >> 4) << 3) + e;
    int f = nt * 16 + (lane & 15);
    wfq[idx] = f2b(w1[c * 256 + f]);
  } else {
    int j = idx - 81920;
    int nt = (j >> 9) & 3, kk = (j >> 11) & 7;
    int f = kk * 32 + ((lane >> 4) << 3) + e;
    int c = nt * 16 + (lane & 15);
    wfq[idx] = f2b(w2[f * 64 + c]);
  }
}

// ------- fused LN1 + window MHA + out-proj + x2 + LN2 + FFN (all MFMA) -------
// one block (4 waves) per window; wave owns 16 token rows. 40KB LDS.
// __launch_bounds__(256,4): 4 waves/EU -> VGPR<=128 -> 4 blocks/CU (LDS 160KB exact)
__global__ __launch_bounds__(256, 4) void k_mega(
    const float* __restrict__ x,
    const float* __restrict__ ln1g, const float* __restrict__ ln1b,
    const float* __restrict__ bq, const float* __restrict__ bk,
    const float* __restrict__ bv, const float* __restrict__ bo,
    const float* __restrict__ ln2g, const float* __restrict__ ln2b,
    const float* __restrict__ b1, const float* __restrict__ b2,
    const u16* __restrict__ wf,
    float* __restrict__ out){
  __shared__ alignas(16) u16 sh[20480];   // 40KB
  u16* hs = sh;           // [64][64] LN1(x); later LN2 result
  u16* qs = sh + 4096;    // Q; later per-head O; later y1 (wg0)
  u16* ks = sh + 8192;    // K; later y1 (wg1)
  u16* vt = sh + 12288;   // V^T; later y1 (wg2)
  u16* ps = sh + 16384;   // P; later y1 (wg3)
  const u16* wfq = wf;
  const u16* wfo = wf + 49152;
  const u16* wf1 = wf + 65536;
  const u16* wf2 = wf + 81920;

  int tid = threadIdx.x, wg = tid >> 6, lane = tid & 63;
  int win = blockIdx.x;
  int d0 = (win >> 8) << 2, h0 = ((win >> 4) & 15) << 2, w0 = (win & 15) << 2;
  int tb = wg * 16;
  int c0 = lane & 15, g4 = (lane >> 4) << 2;

  // ---- load own rows + LN1 -> hs (bf16, swizzled). Own rows: no barrier. ----
  {
    float gv = ln1g[lane], bb = ln1b[lane];
    #pragma unroll
    for (int j = 0; j < 16; ++j){
      int l = tb + j;
      int gd = d0 + (l >> 4), gh = h0 + ((l >> 2) & 3), gw = w0 + (l & 3);
      float v = x[((gd * 64 + gh) * 64 + gw) * 64 + lane];
      float mn = wred_sum(v) * 0.015625f;
      float dv = v - mn;
      float var = wred_sum(dv * dv) * 0.015625f;
      float n = dv * rsqrtf(var + 1e-5f) * gv + bb;
      hs[l * 64 + (lane ^ ((l & 7) << 3))] = f2b(n);
    }
  }

  f32x4 oacc[4];
  #pragma unroll
  for (int ct = 0; ct < 4; ++ct){
    float b0 = bo[ct * 16 + c0];
    oacc[ct] = (f32x4){b0, b0, b0, b0};
  }

  for (int hh = 0; hh < 4; ++hh){
    // ---- QKV projection: three sequential passes (low reg pressure) ----
    #pragma unroll
    for (int m = 0; m < 3; ++m){
      const float* bias = (m == 0) ? bq : ((m == 1) ? bk : bv);
      f32x4 acc[4];
      #pragma unroll
      for (int ct = 0; ct < 4; ++ct){
        float bb = bias[hh * 64 + ct * 16 + c0];
        acc[ct] = (f32x4){bb, bb, bb, bb};
      }
      #pragma unroll
      for (int kk = 0; kk < 2; ++kk){
        bf16x8 a = ldfrag<64>(hs, tb, kk * 32, lane);
        const u16* base = wfq + m * 16384 + ((hh * 2 + kk) * 4) * 512 + lane * 8;
        #pragma unroll
        for (int ct = 0; ct < 4; ++ct)
          acc[ct] = __builtin_amdgcn_mfma_f32_16x16x32_bf16(
              a, *(const bf16x8*)(base + ct * 512), acc[ct], 0, 0, 0);
      }
      if (m == 0){
        #pragma unroll
        for (int ct = 0; ct < 4; ++ct) stfrag<64>(qs, tb, ct * 16, acc[ct], 0.125f, lane);
      } else if (m == 1){
        #pragma unroll
        for (int ct = 0; ct < 4; ++ct) stfrag<64>(ks, tb, ct * 16, acc[ct], 1.0f, lane);
      } else {
        #pragma unroll
        for (int ct = 0; ct < 4; ++ct) stfragT(vt, tb, ct * 16, acc[ct], lane);
      }
    }
    __syncthreads();   // ks/vt read cross-wave

    // ---- att = Q K^T ----
    f32x4 att[4];
    #pragma unroll
    for (int ct = 0; ct < 4; ++ct) att[ct] = (f32x4){0.f, 0.f, 0.f, 0.f};
    #pragma unroll
    for (int kk = 0; kk < 2; ++kk){
      bf16x8 a = ldfrag<64>(qs, tb, kk * 32, lane);
      #pragma unroll
      for (int ct = 0; ct < 4; ++ct)
        att[ct] = __builtin_amdgcn_mfma_f32_16x16x32_bf16(
            a, ldfrag<64>(ks, ct * 16, kk * 32, lane), att[ct], 0, 0, 0);
    }

    // ---- in-register softmax over m ----
    #pragma unroll
    for (int r = 0; r < 4; ++r){
      float m0 = fmaxf(fmaxf(att[0][r], att[1][r]), fmaxf(att[2][r], att[3][r]));
      m0 = fmaxf(m0, __shfl_xor(m0, 1));
      m0 = fmaxf(m0, __shfl_xor(m0, 2));
      m0 = fmaxf(m0, __shfl_xor(m0, 4));
      m0 = fmaxf(m0, __shfl_xor(m0, 8));
      float e0 = expf(att[0][r] - m0), e1 = expf(att[1][r] - m0);
      float e2 = expf(att[2][r] - m0), e3 = expf(att[3][r] - m0);
      float s = grp16_sum(e0 + e1 + e2 + e3);
      float inv = 1.0f / s;
      att[0][r] = e0 * inv; att[1][r] = e1 * inv;
      att[2][r] = e2 * inv; att[3][r] = e3 * inv;
    }
    #pragma unroll
    for (int ct = 0; ct < 4; ++ct) stfrag<64>(ps, tb, ct * 16, att[ct], 1.0f, lane);

    // ---- O_h = P V ----
    f32x4 oh[4];
    #pragma unroll
    for (int ct = 0; ct < 4; ++ct) oh[ct] = (f32x4){0.f, 0.f, 0.f, 0.f};
    #pragma unroll
    for (int kk = 0; kk < 2; ++kk){
      bf16x8 a = ldfrag<64>(ps, tb, kk * 32, lane);
      #pragma unroll
      for (int ct = 0; ct < 4; ++ct)
        oh[ct] = __builtin_amdgcn_mfma_f32_16x16x32_bf16(
            a, ldfrag<64>(vt, ct * 16, kk * 32, lane), oh[ct], 0, 0, 0);
    }
    #pragma unroll
    for (int ct = 0; ct < 4; ++ct) stfrag<64>(qs, tb, ct * 16, oh[ct], 1.0f, lane);

    // ---- out-proj accumulate ----
    #pragma unroll
    for (int kkl = 0; kkl < 2; ++kkl){
      bf16x8 a = ldfrag<64>(qs, tb, kkl * 32, lane);
      const u16* base = wfo + ((hh * 2 + kkl) * 4) * 512 + lane * 8;
      #pragma unroll
      for (int ct = 0; ct < 4; ++ct)
        oacc[ct] = __builtin_amdgcn_mfma_f32_16x16x32_bf16(
            a, *(const bf16x8*)(base + ct * 512), oacc[ct], 0, 0, 0);
    }
    __syncthreads();   // before next head overwrites ks/vt (and before FFN LDS reuse)
  }

  // ======== fused x2 + LN2 + FFN (wave-private from here: no barriers) ========
  {
    float g2[4], b2l[4];
    #pragma unroll
    for (int ct = 0; ct < 4; ++ct){
      g2[ct] = ln2g[ct * 16 + c0];
      b2l[ct] = ln2b[ct * 16 + c0];
    }
    #pragma unroll
    for (int r = 0; r < 4; ++r){
      float v0 = 2.0f * oacc[0][r], v1 = 2.0f * oacc[1][r];
      float v2 = 2.0f * oacc[2][r], v3 = 2.0f * oacc[3][r];
      float s = grp16_sum(v0 + v1 + v2 + v3);
      float mn = s * 0.015625f;
      float d0f = v0 - mn, d1 = v1 - mn, d2 = v2 - mn, d3 = v3 - mn;
      float q = grp16_sum(d0f*d0f + d1*d1 + d2*d2 + d3*d3);
      float rs = rsqrtf(q * 0.015625f + 1e-5f);
      int row = tb + g4 + r;
      hs[row * 64 + ((0 * 16 + c0) ^ ((row & 7) << 3))] = f2b(d0f * rs * g2[0] + b2l[0]);
      hs[row * 64 + ((1 * 16 + c0) ^ ((row & 7) << 3))] = f2b(d1 * rs * g2[1] + b2l[1]);
      hs[row * 64 + ((2 * 16 + c0) ^ ((row & 7) << 3))] = f2b(d2 * rs * g2[2] + b2l[2]);
      hs[row * 64 + ((3 * 16 + c0) ^ ((row & 7) << 3))] = f2b(d3 * rs * g2[3] + b2l[3]);
    }
  }

  // ---- GEMM1: [16,64] x [64,256] -> y1 (GELU, bf16), two 8-tile halves ----
  u16* y1w = sh + 4096 + wg * 4096;   // [16][256] bf16, swizzled
  #pragma unroll
  for (int half = 0; half < 2; ++half){
    f32x4 acc1[8];
    #pragma unroll
    for (int nt = 0; nt < 8; ++nt){
      float bb = b1[(half * 8 + nt) * 16 + c0];
      acc1[nt] = (f32x4){bb, bb, bb, bb};
    }
    #pragma unroll
    for (int kk = 0; kk < 2; ++kk){
      bf16x8 a = ldfrag<64>(hs, tb, kk * 32, lane);
      const u16* base = wf1 + kk * 16 * 512 + half * 8 * 512 + lane * 8;
      #pragma unroll
      for (int nt = 0; nt < 8; ++nt)
        acc1[nt] = __builtin_amdgcn_mfma_f32_16x16x32_bf16(
            a, *(const bf16x8*)(base + nt * 512), acc1[nt], 0, 0, 0);
    }
    #pragma unroll
    for (int nt = 0; nt < 8; ++nt){
      f32x4 v = acc1[nt];
      f32x4 y;
      #pragma unroll
      for (int r = 0; r < 4; ++r) y[r] = gelu(v[r]);
      stfrag<256>(y1w, 0, (half * 8 + nt) * 16, y, 1.0f, lane);
    }
  }

  // ---- GEMM2: [16,256] x [256,64] -> out (fp32, merged voxel layout) ----
  {
    f32x4 acc2[4];
    #pragma unroll
    for (int nt = 0; nt < 4; ++nt){
      float bb = b2[nt * 16 + c0];
      acc2[nt] = (f32x4){bb, bb, bb, bb};
    }
    #pragma unroll
    for (int kk = 0; kk < 8; ++kk){
      bf16x8 a = ldfrag<256>(y1w, 0, kk * 32, lane);
      const u16* base = wf2 + kk * 4 * 512 + lane * 8;
      #pragma unroll
      for (int nt = 0; nt < 4; ++nt)
        acc2[nt] = __builtin_amdgcn_mfma_f32_16x16x32_bf16(
            a, *(const bf16x8*)(base + nt * 512), acc2[nt], 0, 0, 0);
    }
    #pragma unroll
    for (int r = 0; r < 4; ++r){
      int l = tb + g4 + r;
      int gd = d0 + (l >> 4), gh = h0 + ((l >> 2) & 3), gw = w0 + (l & 3);
      float* orow = out + ((gd * 64 + gh) * 64 + gw) * 64;
      #pragma unroll
      for (int nt = 0; nt < 4; ++nt)
        orow[nt * 16 + c0] = acc2[nt][r];
    }
  }
}

extern "C" void kernel_launch(void* const* d_in, const int* in_sizes, int n_in,
                              void* d_out, int out_size, void* d_ws, size_t ws_size,
                              hipStream_t stream){
  const float* x    = (const float*)d_in[0];
  const float* ln1g = (const float*)d_in[1];
  const float* ln1b = (const float*)d_in[2];
  const float* wq   = (const float*)d_in[3];
  const float* bq   = (const float*)d_in[4];
  const float* wk   = (const float*)d_in[5];
  const float* bk   = (const float*)d_in[6];
  const float* wv   = (const float*)d_in[7];
  const float* bv   = (const float*)d_in[8];
  const float* wo   = (const float*)d_in[9];
  const float* bo   = (const float*)d_in[10];
  const float* ln2g = (const float*)d_in[11];
  const float* ln2b = (const float*)d_in[12];
  const float* w1   = (const float*)d_in[13];
  const float* b1   = (const float*)d_in[14];
  const float* w2   = (const float*)d_in[15];
  const float* b2   = (const float*)d_in[16];

  u16* wf = (u16*)d_ws;     // 192KB of bf16 weight fragments
  float* out = (float*)d_out;

  k_prep<<<384, 256, 0, stream>>>(wq, wk, wv, wo, w1, w2, wf);
  k_mega<<<NWIN, 256, 0, stream>>>(x, ln1g, ln1b, bq, bk, bv, bo,
                                   ln2g, ln2b, b1, b2, wf, out);
}